// Round 14
// baseline (611.558 us; speedup 1.0000x reference)
//
#include <hip/hip_runtime.h>
#include <hip/hip_bf16.h>

#define TT 512
#define DD 512
#define VV 2048
#define HH 128

typedef __attribute__((ext_vector_type(8))) short bf16x8;
typedef __attribute__((ext_vector_type(8))) unsigned short ushort8;
typedef __attribute__((ext_vector_type(4))) unsigned short ushort4v;
typedef __attribute__((ext_vector_type(4))) float f32x4;

__device__ __forceinline__ unsigned short f2bf(float f) {
  union { __hip_bfloat16 b; unsigned short u; } cv;
  cv.b = __float2bfloat16(f);
  return cv.u;
}

// LDS-only barrier (fallback kernel): orders ds ops without draining vmcnt.
__device__ __forceinline__ void lds_barrier() {
  asm volatile("s_waitcnt lgkmcnt(0)\n\ts_barrier" ::: "memory");
}

#define VM_GATE(N)                                                   \
  do {                                                               \
    asm volatile("s_waitcnt vmcnt(" #N ")" ::: "memory");            \
    __builtin_amdgcn_sched_barrier(0);                               \
  } while (0)

__global__ void cvt_x_kernel(const float* __restrict__ x, unsigned short* __restrict__ xb) {
  const int i = blockIdx.x * blockDim.x + threadIdx.x;
  const float4 f = ((const float4*)x)[i];
  ushort4v u;
  u[0] = f2bf(f.x); u[1] = f2bf(f.y); u[2] = f2bf(f.z); u[3] = f2bf(f.w);
  ((ushort4v*)xb)[i] = u;
}

// One-shot weight conversion: W1 (16 k-tiles) + W2 (4 k-tiles) per voxel ->
// bf16 in MFMA-frag-linear layout. WG g = v*20 + tile handles one 32x128
// fp32 tile: coalesced float4 reads -> LDS frag scatter -> coalesced write.
// Frag mapping (== R13's verified CVT): chunk(tile,n) holds, at lane l elem j,
// W[k = (l>>4)*8 + j][h = n*16 + (l&15)]  (1 KiB contiguous per chunk).
__global__ __launch_bounds__(256)
void cvt_w_kernel(const float* __restrict__ W1, const float* __restrict__ W2,
                  unsigned short* __restrict__ wb) {
  const int g    = blockIdx.x;
  const int v    = g / 20;
  const int tile = g % 20;
  const float* src = (tile < 16)
      ? (W1 + (size_t)v * DD * HH + (size_t)tile * 32 * HH)
      : (W2 + (size_t)v * HH * HH + (size_t)(tile - 16) * 32 * HH);

  __shared__ __align__(16) unsigned short F[4096];   // 8 KiB frag tile
  const int tid = threadIdx.x;
#pragma unroll
  for (int q = 0; q < 4; ++q) {
    const int idx = tid + q * 256;     // 1024 float4 = 32 rows x 32
    const int k   = idx >> 5;
    const int c4  = idx & 31;
    const float4 f = *(const float4*)(src + k * HH + c4 * 4);
#pragma unroll
    for (int c = 0; c < 4; ++c) {
      const int h = c4 * 4 + c;
      const int n = h >> 4;
      const int l = ((k & 31) >> 3) * 16 + (h & 15);
      const int j = k & 7;
      const float fv = (c == 0) ? f.x : (c == 1) ? f.y : (c == 2) ? f.z : f.w;
      F[(n * 64 + l) * 8 + j] = f2bf(fv);
    }
  }
  __syncthreads();
  unsigned short* d = wb + (size_t)g * 4096 + tid * 16;
  *(ushort8*)(d)     = *(const ushort8*)(F + tid * 16);
  *(ushort8*)(d + 8) = *(const ushort8*)(F + tid * 16 + 8);
}

// Main kernel (ws path): 1 WG = 1 voxel, 512 thr = 8 waves, wave w owns
// t-rows [w*64,+64). ZERO barriers: B-frags are direct coalesced b128 loads
// from frag-linear bf16 weights (L2-dedup'd across the 8 waves); A-frags
// from L2-resident Xb; h1 in wave-private LDS slots (same-wave lgkmcnt only).
__global__ __launch_bounds__(512, 2)
void voxel_mlp_ws(const unsigned short* __restrict__ Xb,
                  const unsigned short* __restrict__ Wb,
                  const float* __restrict__ b1,
                  const float* __restrict__ b2,
                  const float* __restrict__ W3,
                  const float* __restrict__ b3,
                  float* __restrict__ out) {
  __shared__ __align__(16) char LDS[32768];   // h1: 8 waves x 4 KiB

  const int v   = blockIdx.x;
  const int tid = threadIdx.x;
  const int w   = tid >> 6;
  const int l   = tid & 63;
  const int lg  = l >> 4;
  const int ll  = l & 15;

  const unsigned short* Wv = Wb + (size_t)v * 81920;   // 20 tiles * 4096 ushort

  f32x4 acc1[4][8];
#pragma unroll
  for (int mi = 0; mi < 4; ++mi)
#pragma unroll
    for (int n = 0; n < 8; ++n) acc1[mi][n] = f32x4{0.f, 0.f, 0.f, 0.f};

  // ---- phase A: layer 1, 16 steps of BK=32, barrier-free ----
#pragma unroll
  for (int s = 0; s < 16; ++s) {
    bf16x8 aF[4];
#pragma unroll
    for (int mi = 0; mi < 4; ++mi)
      aF[mi] = *(const bf16x8*)(Xb + (size_t)(w * 64 + mi * 16 + ll) * DD +
                                s * 32 + lg * 8);
#pragma unroll
    for (int n = 0; n < 8; ++n) {
      const bf16x8 b = *(const bf16x8*)(Wv + ((size_t)s * 8 + n) * 512 + l * 8);
#pragma unroll
      for (int mi = 0; mi < 4; ++mi)
        acc1[mi][n] = __builtin_amdgcn_mfma_f32_16x16x32_bf16(aF[mi], b, acc1[mi][n], 0, 0, 0);
    }
  }

  float b1v[8], b2v[8], w3v[8];
#pragma unroll
  for (int n = 0; n < 8; ++n) {
    b1v[n] = b1[v * HH + n * 16 + ll];
    b2v[n] = b2[v * HH + n * 16 + ll];
    w3v[n] = W3[v * HH + n * 16 + ll];
  }
  const float b3v = b3[v];

  const unsigned slot = (unsigned)w * 4096u;   // wave-private 16x128 bf16

  // ---- phase B: layers 2+3, wave-private, barrier-free ----
#pragma unroll
  for (int mi = 0; mi < 4; ++mi) {
#pragma unroll
    for (int n = 0; n < 8; ++n) {
#pragma unroll
      for (int r = 0; r < 4; ++r) {
        const int tl = lg * 4 + r;
        float hv = acc1[mi][n][r] + b1v[n];
        hv = fmaxf(hv, 0.f);
        const int h = n * 16 + ll;
        const unsigned byte = slot + (unsigned)tl * 256u +
                              (unsigned)((h * 2) ^ ((tl & 7) << 4));
        *(unsigned short*)(&LDS[byte]) = f2bf(hv);
      }
    }
    f32x4 acc2[8];
#pragma unroll
    for (int m = 0; m < 8; ++m) acc2[m] = f32x4{0.f, 0.f, 0.f, 0.f};
#pragma unroll
    for (int ki = 0; ki < 4; ++ki) {
      const int k0 = ki * 32 + lg * 8;
      const unsigned abyte = slot + (unsigned)ll * 256u +
                             (unsigned)((k0 * 2) ^ ((ll & 7) << 4));
      const bf16x8 a2 = *(const bf16x8*)(&LDS[abyte]);
#pragma unroll
      for (int m = 0; m < 8; ++m) {
        const bf16x8 bw = *(const bf16x8*)(Wv + ((size_t)(16 + ki) * 8 + m) * 512 + l * 8);
        acc2[m] = __builtin_amdgcn_mfma_f32_16x16x32_bf16(a2, bw, acc2[m], 0, 0, 0);
      }
    }
#pragma unroll
    for (int r = 0; r < 4; ++r) {
      float p = 0.f;
#pragma unroll
      for (int m = 0; m < 8; ++m)
        p += fmaxf(acc2[m][r] + b2v[m], 0.f) * w3v[m];
      p += __shfl_xor(p, 1);
      p += __shfl_xor(p, 2);
      p += __shfl_xor(p, 4);
      p += __shfl_xor(p, 8);
      if (ll == 0) {
        const int t = w * 64 + mi * 16 + lg * 4 + r;
        out[t * VV + v] = p + b3v;
      }
    }
  }
}

// ---------------- fallback (exact R13, used when ws is too small) ----------
__global__ __launch_bounds__(256, 2)
void voxel_mlp_fb(const unsigned short* __restrict__ Xb,
                  const float* __restrict__ W1,
                  const float* __restrict__ b1,
                  const float* __restrict__ W2,
                  const float* __restrict__ b2,
                  const float* __restrict__ W3,
                  const float* __restrict__ b3,
                  float* __restrict__ out) {
  __shared__ __align__(16) char LDS[66304];
  constexpr unsigned GBASE  = 0;
  constexpr unsigned GSLOT  = 16640;
  constexpr unsigned FBASE  = 49920;
  constexpr unsigned W2BASE = 0;
  constexpr unsigned H1BASE = 32768;

  const int bid  = blockIdx.x;
  const int xcd  = bid & 7;
  const int gg   = bid >> 3;
  const int half = gg & 1;
  const int v    = (gg >> 1) * 8 + xcd;

  const int tid = threadIdx.x;
  const int w   = tid >> 6;
  const int l   = tid & 63;
  const int lg  = l >> 4;
  const int ll  = l & 15;

  const float* W1v = W1 + (size_t)v * DD * HH;
  const float* W2v = W2 + (size_t)v * HH * HH;
  const size_t gsrc = (size_t)(w * 8) * HH + (size_t)l * 4;

#define G_ISSUE(t)                                                          \
  { const float* gp = W1v + (size_t)(t) * 32 * HH + gsrc;                   \
    const unsigned ld0 = GBASE + (unsigned)((t) % 3) * GSLOT +              \
                         (unsigned)(w * 4) * 1040u;                         \
    _Pragma("unroll") for (int p = 0; p < 4; ++p)                           \
      __builtin_amdgcn_global_load_lds(                                     \
        (const __attribute__((address_space(1))) void*)(gp + p * 2 * HH),   \
        (__attribute__((address_space(3))) void*)(&LDS[ld0 + (unsigned)p * 1040u]), \
        16, 0, 0); }

#define CVT(tau)                                                            \
  { const unsigned gs = GBASE + (unsigned)((tau) % 3) * GSLOT;              \
    _Pragma("unroll") for (int p = 0; p < 2; ++p) {                         \
      const int n = w + p * 4;                                              \
      ushort8 e;                                                            \
      _Pragma("unroll") for (int j = 0; j < 8; ++j) {                       \
        const int k = lg * 8 + j;                                           \
        const unsigned u = *(const unsigned*)(&LDS[gs +                     \
            (unsigned)((k >> 1) * 1040 + (k & 1) * 512 + (n * 16 + ll) * 4)]); \
        e[j] = (unsigned short)((u + 0x8000u) >> 16);                       \
      }                                                                     \
      *(ushort8*)(&LDS[FBASE + (unsigned)((tau) & 1) * 8192u +              \
                       (unsigned)n * 1024u + (unsigned)l * 16u]) = e;       \
    } }

#define ISSUE_A(st)                                                         \
  { _Pragma("unroll") for (int mi = 0; mi < 4; ++mi)                        \
      aS[(st) & 1][mi] = *(const bf16x8*)(Xb +                              \
          (size_t)(half * 256 + w * 64 + mi * 16 + ll) * DD +               \
          (st) * 32 + lg * 8); }

  bf16x8 aS[2][4];
  G_ISSUE(0);
  G_ISSUE(1);
  ISSUE_A(0);
  VM_GATE(8);
  lds_barrier();
  CVT(0);

  f32x4 acc1[4][8];
#pragma unroll
  for (int mi = 0; mi < 4; ++mi)
#pragma unroll
    for (int n = 0; n < 8; ++n) acc1[mi][n] = f32x4{0.f, 0.f, 0.f, 0.f};

#pragma unroll
  for (int s = 0; s < 16; ++s) {
    if (s < 14) G_ISSUE(s + 2);
    if (s < 15) ISSUE_A(s + 1);
    if (s < 14)      { VM_GATE(8); }
    else if (s == 14){ VM_GATE(4); }
    else             { VM_GATE(0); }
    lds_barrier();
    if (s < 15) CVT(s + 1);
#pragma unroll
    for (int n = 0; n < 8; ++n) {
      const bf16x8 b = *(const bf16x8*)(&LDS[FBASE + (unsigned)(s & 1) * 8192u +
                                             (unsigned)n * 1024u + (unsigned)l * 16u]);
#pragma unroll
      for (int mi = 0; mi < 4; ++mi)
        acc1[mi][n] = __builtin_amdgcn_mfma_f32_16x16x32_bf16(aS[s & 1][mi], b, acc1[mi][n], 0, 0, 0);
    }
  }
#undef G_ISSUE
#undef CVT
#undef ISSUE_A

  float b1v[8], b2v[8], w3v[8];
#pragma unroll
  for (int n = 0; n < 8; ++n) {
    b1v[n] = b1[v * HH + n * 16 + ll];
    b2v[n] = b2[v * HH + n * 16 + ll];
    w3v[n] = W3[v * HH + n * 16 + ll];
  }
  const float b3v = b3[v];

#pragma unroll
  for (int pass = 0; pass < 2; ++pass) {
    float w2t[4][8];
#pragma unroll
    for (int q = 0; q < 4; ++q)
#pragma unroll
      for (int j = 0; j < 8; ++j)
        w2t[q][j] = W2v[(w * 32 + lg * 8 + j) * HH + (pass * 4 + q) * 16 + ll];
#pragma unroll
    for (int q = 0; q < 4; ++q) {
      ushort8 e;
#pragma unroll
      for (int j = 0; j < 8; ++j) e[j] = f2bf(w2t[q][j]);
      *(ushort8*)(&LDS[W2BASE + (unsigned)w * 8192u + (unsigned)(pass * 4 + q) * 1024u +
                       (unsigned)l * 16u]) = e;
    }
  }
  lds_barrier();

  const unsigned slot = H1BASE + (unsigned)w * 4096u;
#pragma unroll
  for (int mi = 0; mi < 4; ++mi) {
#pragma unroll
    for (int n = 0; n < 8; ++n) {
#pragma unroll
      for (int r = 0; r < 4; ++r) {
        const int tl = lg * 4 + r;
        float hv = acc1[mi][n][r] + b1v[n];
        hv = fmaxf(hv, 0.f);
        const int h = n * 16 + ll;
        const unsigned byte = slot + (unsigned)tl * 256u +
                              (unsigned)((h * 2) ^ ((tl & 7) << 4));
        *(unsigned short*)(&LDS[byte]) = f2bf(hv);
      }
    }
    f32x4 acc2[8];
#pragma unroll
    for (int m = 0; m < 8; ++m) acc2[m] = f32x4{0.f, 0.f, 0.f, 0.f};
#pragma unroll
    for (int ki = 0; ki < 4; ++ki) {
      const int k0 = ki * 32 + lg * 8;
      const unsigned abyte = slot + (unsigned)ll * 256u +
                             (unsigned)((k0 * 2) ^ ((ll & 7) << 4));
      const bf16x8 a2 = *(const bf16x8*)(&LDS[abyte]);
#pragma unroll
      for (int m = 0; m < 8; ++m) {
        const bf16x8 bw = *(const bf16x8*)(&LDS[W2BASE + (unsigned)ki * 8192u +
                                                (unsigned)m * 1024u + (unsigned)l * 16u]);
        acc2[m] = __builtin_amdgcn_mfma_f32_16x16x32_bf16(a2, bw, acc2[m], 0, 0, 0);
      }
    }
#pragma unroll
    for (int r = 0; r < 4; ++r) {
      float p = 0.f;
#pragma unroll
      for (int m = 0; m < 8; ++m)
        p += fmaxf(acc2[m][r] + b2v[m], 0.f) * w3v[m];
      p += __shfl_xor(p, 1);
      p += __shfl_xor(p, 2);
      p += __shfl_xor(p, 4);
      p += __shfl_xor(p, 8);
      if (ll == 0) {
        const int t = half * 256 + w * 64 + mi * 16 + lg * 4 + r;
        out[t * VV + v] = p + b3v;
      }
    }
  }
}

extern "C" void kernel_launch(void* const* d_in, const int* in_sizes, int n_in,
                              void* d_out, int out_size, void* d_ws, size_t ws_size,
                              hipStream_t stream) {
  const float* X  = (const float*)d_in[0];
  const float* W1 = (const float*)d_in[1];
  const float* b1 = (const float*)d_in[2];
  const float* W2 = (const float*)d_in[3];
  const float* b2 = (const float*)d_in[4];
  const float* W3 = (const float*)d_in[5];
  const float* b3 = (const float*)d_in[6];
  float* out = (float*)d_out;

  unsigned short* Xb = (unsigned short*)d_ws;       // [0, 512 KiB): bf16 X
  const size_t NEED = 524288ull + 2048ull * 20 * 8192;   // + 320 MiB frag weights

  cvt_x_kernel<<<256, 256, 0, stream>>>(X, Xb);

  if (ws_size >= NEED) {
    unsigned short* Wbp = (unsigned short*)d_ws + 262144;   // byte 524288
    cvt_w_kernel<<<2048 * 20, 256, 0, stream>>>(W1, W2, Wbp);
    voxel_mlp_ws<<<VV, 512, 0, stream>>>(Xb, Wbp, b1, b2, W3, b3, out);
  } else {
    voxel_mlp_fb<<<VV * 2, 256, 0, stream>>>(Xb, W1, b1, W2, b2, W3, b3, out);
  }
}

// Round 15
// 500.156 us; speedup vs baseline: 1.2227x; 1.2227x over previous
//
#include <hip/hip_runtime.h>
#include <hip/hip_bf16.h>

#define TT 512
#define DD 512
#define VV 2048
#define HH 128

typedef __attribute__((ext_vector_type(8))) short bf16x8;
typedef __attribute__((ext_vector_type(8))) unsigned short ushort8;
typedef __attribute__((ext_vector_type(4))) unsigned short ushort4v;
typedef __attribute__((ext_vector_type(4))) float f32x4;

__device__ __forceinline__ unsigned short f2bf(float f) {
  union { __hip_bfloat16 b; unsigned short u; } cv;
  cv.b = __float2bfloat16(f);
  return cv.u;
}

// LDS-only barrier: orders ds ops across waves without draining vmcnt.
__device__ __forceinline__ void lds_barrier() {
  asm volatile("s_waitcnt lgkmcnt(0)\n\ts_barrier" ::: "memory");
}

// Counted vmem gate (per-wave FIFO): keep the youngest N vmem ops in flight.
#define VM_GATE(N)                                                   \
  do {                                                               \
    asm volatile("s_waitcnt vmcnt(" #N ")" ::: "memory");            \
    __builtin_amdgcn_sched_barrier(0);                               \
  } while (0)

__global__ void cvt_x_kernel(const float* __restrict__ x, unsigned short* __restrict__ xb) {
  const int i = blockIdx.x * blockDim.x + threadIdx.x;
  const float4 f = ((const float4*)x)[i];
  ushort4v u;
  u[0] = f2bf(f.x); u[1] = f2bf(f.y); u[2] = f2bf(f.z); u[3] = f2bf(f.w);
  ((ushort4v*)xb)[i] = u;
}

// 2 WGs per voxel (half = 256 t-rows), XCD-twinned for W1 L2-dedup.
// WG = 512 thr = 8 waves in a 4M x 2N grid: wave w = rows [(w>>1)*64,+64) x
// cols [(w&1)*64,+64). acc1[4][4] = 64 VGPR -> total <=128 -> 4 waves/SIMD,
// 2 WGs/CU = 16 waves (2x R13's TLP; two independent barrier domains).
// Phase A (16 steps, BK=32): R13's verified pipeline verbatim — G ring-3
// (1040-B pad, 2-way-free transpose CVT), global_load_lds, per-step
// {A(4), G(s+2)(2), VM_GATE(2), barrier, CVT(s+1), 16 MFMA}, 1 barrier/step.
// Phase B: W2L frag-linear + h1 in two 128-row halves (8 x 4 KiB slots).
// LDS 64.75 KiB: G ring3 [0,49920) + F dbuf [49920,66304)  (phase A)
//                W2L [0,32768) + h1 [32768,65536)          (phase B)
__global__ __launch_bounds__(512, 4)
void voxel_mlp_kernel(const unsigned short* __restrict__ Xb,
                      const float* __restrict__ W1,
                      const float* __restrict__ b1,
                      const float* __restrict__ W2,
                      const float* __restrict__ b2,
                      const float* __restrict__ W3,
                      const float* __restrict__ b3,
                      float* __restrict__ out) {
  __shared__ __align__(16) char LDS[66304];
  constexpr unsigned GBASE  = 0;
  constexpr unsigned GSLOT  = 16640;   // 16 row-pairs x 1040 B
  constexpr unsigned FBASE  = 49920;   // 2 x 8192
  constexpr unsigned W2BASE = 0;
  constexpr unsigned H1BASE = 32768;

  const int bid  = blockIdx.x;
  const int xcd  = bid & 7;
  const int g    = bid >> 3;
  const int half = g & 1;
  const int v    = (g >> 1) * 8 + xcd;   // twins 8 bids apart -> same XCD

  const int tid = threadIdx.x;
  const int w   = tid >> 6;    // wave 0..7
  const int l   = tid & 63;
  const int lg  = l >> 4;
  const int ll  = l & 15;
  const int wm  = w >> 1;      // M-band 0..3 (64 rows)
  const int wn  = w & 1;       // N-half 0..1 (64 cols)

  const float* W1v = W1 + (size_t)v * DD * HH;
  const float* W2v = W2 + (size_t)v * HH * HH;

  // DMA src: wave w covers rows 4w..4w+3 of the 32x128 tile; instr q = rows
  // {4w+2q, +1} (1 KB contiguous); lane l -> 16 B at (l>>5) row, (l&31) dword4.
  const size_t gsrc = (size_t)(w * 4) * HH + (size_t)(l >> 5) * HH + (size_t)(l & 31) * 4;

#define G_ISSUE(t)                                                          \
  { const float* gp = W1v + (size_t)(t) * 32 * HH + gsrc;                   \
    const unsigned ld0 = GBASE + (unsigned)((t) % 3) * GSLOT +              \
                         (unsigned)(w * 2) * 1040u;                         \
    _Pragma("unroll") for (int q = 0; q < 2; ++q)                           \
      __builtin_amdgcn_global_load_lds(                                     \
        (const __attribute__((address_space(1))) void*)(gp + q * 2 * HH),   \
        (__attribute__((address_space(3))) void*)(&LDS[ld0 + (unsigned)q * 1040u]), \
        16, 0, 0); }

// transpose-convert tile tau: thread (w,l) builds frag chunk n = w
// (h = w*16+ll, k = lg*8+j). Banks 2-way (free) via the 1040 pad.
#define CVT(tau)                                                            \
  { const unsigned gs = GBASE + (unsigned)((tau) % 3) * GSLOT;              \
    ushort8 e;                                                              \
    _Pragma("unroll") for (int j = 0; j < 8; ++j) {                         \
      const int k = lg * 8 + j;                                             \
      const unsigned u = *(const unsigned*)(&LDS[gs +                       \
          (unsigned)((k >> 1) * 1040 + (k & 1) * 512 + (w * 16 + ll) * 4)]); \
      e[j] = (unsigned short)((u + 0x8000u) >> 16);                         \
    }                                                                       \
    *(ushort8*)(&LDS[FBASE + (unsigned)((tau) & 1) * 8192u +                \
                     (unsigned)w * 1024u + (unsigned)l * 16u]) = e; }

#define ISSUE_A(st)                                                         \
  { _Pragma("unroll") for (int mi = 0; mi < 4; ++mi)                        \
      aF[mi] = *(const bf16x8*)(Xb +                                        \
          (size_t)(half * 256 + wm * 64 + mi * 16 + ll) * DD +              \
          (st) * 32 + lg * 8); }

  bf16x8 aF[4];

  // ---- prologue ----
  G_ISSUE(0);
  G_ISSUE(1);
  VM_GATE(2);       // G(0) landed; keep G(1)
  lds_barrier();    // G(0) visible across waves
  CVT(0);           // -> F[0]

  f32x4 acc1[4][4];
#pragma unroll
  for (int mi = 0; mi < 4; ++mi)
#pragma unroll
    for (int n = 0; n < 4; ++n) acc1[mi][n] = f32x4{0.f, 0.f, 0.f, 0.f};

  // ---- phase A: 16 steps of BK=32, ONE barrier per step ----
#pragma unroll
  for (int s = 0; s < 16; ++s) {
    ISSUE_A(s);                       // 4 ops, oldest of this step
    if (s < 14) G_ISSUE(s + 2);       // 2 ops, youngest
    if (s < 15) { VM_GATE(2); }       // retire G(s+1)+A(s); keep G(s+2)
    else        { VM_GATE(0); }
    lds_barrier();                    // G(s+1) + F[s&1] visible to all

    if (s < 15) CVT(s + 1);           // slot (s+1)%3 -> F[(s+1)&1]

    // 16 MFMAs on F[s&1], chunks n = wn*4..+4
#pragma unroll
    for (int n = 0; n < 4; ++n) {
      const bf16x8 b = *(const bf16x8*)(&LDS[FBASE + (unsigned)(s & 1) * 8192u +
                                             (unsigned)(wn * 4 + n) * 1024u +
                                             (unsigned)l * 16u]);
#pragma unroll
      for (int mi = 0; mi < 4; ++mi)
        acc1[mi][n] = __builtin_amdgcn_mfma_f32_16x16x32_bf16(aF[mi], b, acc1[mi][n], 0, 0, 0);
    }
  }
#undef G_ISSUE
#undef CVT
#undef ISSUE_A

  lds_barrier();   // all F reads done; G/F regions dead

  // ---- phase B setup ----
  float b1v[4];
#pragma unroll
  for (int n = 0; n < 4; ++n) b1v[n] = b1[v * HH + wn * 64 + n * 16 + ll];
  float b2v[8], w3v[8];
#pragma unroll
  for (int m = 0; m < 8; ++m) {
    b2v[m] = b2[v * HH + m * 16 + ll];
    w3v[m] = W3[v * HH + m * 16 + ll];
  }
  const float b3v = b3[v];

  // W2 -> LDS frag-linear [ki][m]: wave w stages ki=w&3, m-blocks (w>>2)*4+q
  {
    const int ki = w & 3, mb = (w >> 2) * 4;
#pragma unroll
    for (int q = 0; q < 4; ++q) {
      float w2t[8];
#pragma unroll
      for (int j = 0; j < 8; ++j)
        w2t[j] = W2v[(ki * 32 + lg * 8 + j) * HH + (mb + q) * 16 + ll];
      ushort8 e;
#pragma unroll
      for (int j = 0; j < 8; ++j) e[j] = f2bf(w2t[j]);
      *(ushort8*)(&LDS[W2BASE + (unsigned)ki * 8192u + (unsigned)(mb + q) * 1024u +
                       (unsigned)l * 16u]) = e;
    }
  }

  // ---- phase B: two halves of 128 rows ----
#pragma unroll
  for (int Hh = 0; Hh < 2; ++Hh) {
    // h1 writes: producer waves w in [4Hh, 4Hh+4)
    if ((w >> 2) == Hh) {
#pragma unroll
      for (int mi = 0; mi < 4; ++mi) {
        const int blk = ((w >> 1) & 1) * 4 + mi;   // 0..7 within half
#pragma unroll
        for (int n = 0; n < 4; ++n) {
          const int h = wn * 64 + n * 16 + ll;
#pragma unroll
          for (int r = 0; r < 4; ++r) {
            const int tl = lg * 4 + r;
            float hv = acc1[mi][n][r] + b1v[n];
            hv = fmaxf(hv, 0.f);
            const unsigned byte = H1BASE + (unsigned)blk * 4096u +
                                  (unsigned)tl * 256u +
                                  (unsigned)((h * 2) ^ ((tl & 7) << 4));
            *(unsigned short*)(&LDS[byte]) = f2bf(hv);
          }
        }
      }
    }
    lds_barrier();   // W2L (first iter) + h1 half visible

    // layer 2: wave w owns block w (rows Hh*128 + w*16 .. +16), all 128 cols
    f32x4 acc2[8];
#pragma unroll
    for (int m = 0; m < 8; ++m) acc2[m] = f32x4{0.f, 0.f, 0.f, 0.f};
#pragma unroll
    for (int ki = 0; ki < 4; ++ki) {
      const int k0 = ki * 32 + lg * 8;
      const unsigned abyte = H1BASE + (unsigned)w * 4096u + (unsigned)ll * 256u +
                             (unsigned)((k0 * 2) ^ ((ll & 7) << 4));
      const bf16x8 a2 = *(const bf16x8*)(&LDS[abyte]);
#pragma unroll
      for (int m = 0; m < 8; ++m) {
        const bf16x8 bw = *(const bf16x8*)(&LDS[W2BASE + (unsigned)ki * 8192u +
                                                (unsigned)m * 1024u + (unsigned)l * 16u]);
        acc2[m] = __builtin_amdgcn_mfma_f32_16x16x32_bf16(a2, bw, acc2[m], 0, 0, 0);
      }
    }
    lds_barrier();   // h1 reads done; next half may overwrite

    // layer 3: relu(acc2+b2).w3 over 128 cols, in-wave reduce, lane0 stores
#pragma unroll
    for (int r = 0; r < 4; ++r) {
      float p = 0.f;
#pragma unroll
      for (int m = 0; m < 8; ++m)
        p += fmaxf(acc2[m][r] + b2v[m], 0.f) * w3v[m];
      p += __shfl_xor(p, 1);
      p += __shfl_xor(p, 2);
      p += __shfl_xor(p, 4);
      p += __shfl_xor(p, 8);
      if (ll == 0) {
        const int t = half * 256 + Hh * 128 + w * 16 + lg * 4 + r;
        out[t * VV + v] = p + b3v;
      }
    }
  }
}

extern "C" void kernel_launch(void* const* d_in, const int* in_sizes, int n_in,
                              void* d_out, int out_size, void* d_ws, size_t ws_size,
                              hipStream_t stream) {
  const float* X  = (const float*)d_in[0];
  const float* W1 = (const float*)d_in[1];
  const float* b1 = (const float*)d_in[2];
  const float* W2 = (const float*)d_in[3];
  const float* b2 = (const float*)d_in[4];
  const float* W3 = (const float*)d_in[5];
  const float* b3 = (const float*)d_in[6];
  float* out = (float*)d_out;

  unsigned short* Xb = (unsigned short*)d_ws;   // 512 KiB bf16 X

  cvt_x_kernel<<<256, 256, 0, stream>>>(X, Xb);
  voxel_mlp_kernel<<<VV * 2, 512, 0, stream>>>(Xb, W1, b1, W2, b2, W3, b3, out);
}